// Round 1
// baseline (132.872 us; speedup 1.0000x reference)
//
#include <hip/hip_runtime.h>
#include <float.h>

#define K_CODES 1024
#define DIM 64
#define T_LEN 8192
#define N_TOK 131072          // 16 * 8192 tokens
#define LO_SCALE 2048.0f
#define NT_LDS 36             // B tiles staged in LDS once (36 * 4 KB = 144 KB)
#define LDS_BYTES (NT_LDS * 4096 + 4096 + 2048)   // tiles + esq(4K) + idx(2K) = 153600

typedef _Float16 half8 __attribute__((ext_vector_type(8)));  // 4 VGPRs: MFMA A/B frag
typedef float    f32x4 __attribute__((ext_vector_type(4)));  // MFMA C/D frag

#define MFMA16(a, b, c) __builtin_amdgcn_mfma_f32_16x16x32_f16((a), (b), (c), 0, 0, 0)

// ---------------- prep: codebook -> tiled f16 hi/lo + 2048*e_sq ----------------
// Tile ct (16 codes) = 4 KB contiguous: hi[q=0..7][code=0..15][j=0..7], lo(x2048) at +1024.
// wesq stores 2048*||e||^2 (exact power-of-2 scale) for the scaled-score argmin.
__global__ void vq_prep(const float* __restrict__ cb,
                        _Float16* __restrict__ w,
                        float* __restrict__ wesq) {
    __shared__ float part[128];
    const int ct   = blockIdx.x;
    const int r    = threadIdx.x;
    const int halF = r >> 7;
    const int rr   = r & 127;
    const int q    = rr >> 4;
    const int code = rr & 15;

    const float* src = cb + (size_t)(ct * 16 + code) * DIM + q * 8;
    float4 v0 = *reinterpret_cast<const float4*>(src);
    float4 v1 = *reinterpret_cast<const float4*>(src + 4);
    float x[8] = {v0.x, v0.y, v0.z, v0.w, v1.x, v1.y, v1.z, v1.w};

    half8 o;
    float psum = 0.0f;
    #pragma unroll
    for (int j = 0; j < 8; ++j) {
        _Float16 h = (_Float16)x[j];
        o[j] = halF ? (_Float16)((x[j] - (float)h) * LO_SCALE) : h;  // (x-h) exact in fp32
        psum = fmaf(x[j], x[j], psum);
    }
    *reinterpret_cast<half8*>(w + (size_t)ct * 2048 + halF * 1024 + q * 128 + code * 8) = o;

    if (halF == 0) part[rr] = psum;
    __syncthreads();
    if (r < 16) {
        float s = 0.0f;
        #pragma unroll
        for (int q2 = 0; q2 < 8; ++q2) s += part[q2 * 16 + r];
        wesq[ct * 16 + r] = s * LO_SCALE;   // pre-scaled: score' = 2048 * score
    }
}

// ---------------- main: one-time LDS stage of 36/64 B tiles + global ping-pong ----------------
// r6-r9 lesson kept: NO loop barriers (free-drifting waves). New: 512-thr blocks (1 block/CU,
// grid=256, still 8 waves/CU) unlock the full 160 KB LDS; tiles 0..35 are staged ONCE behind a
// single barrier and read via ds_read_b128 (16B/lane contiguous = conflict-free), killing the
// L1/L2 load-latency stalls of the 2-deep global ping-pong for 56% of B traffic. Tiles 36..63
// keep the verified global path. Numerics identical to the r9 kernel (exact f16 product set).
__global__ __launch_bounds__(512, 2)
void vq_main(const float* __restrict__ in,
             const float* __restrict__ cb,
             const _Float16* __restrict__ w,
             const float* __restrict__ wesq,
             float* __restrict__ out) {
    extern __shared__ __align__(16) char smem[];
    _Float16* wlds  = (_Float16*)smem;                      // 144 KB: tiles 0..35
    float*    esq_s = (float*)(smem + NT_LDS * 4096);       // 4 KB (scaled x2048)
    int*      idx_s = (int*)(smem + NT_LDS * 4096 + 4096);  // 2 KB

    const int tid  = threadIdx.x;
    const int wave = tid >> 6;
    const int lane = tid & 63;
    const int lo4  = lane & 15;   // code residue (C col) / token residue (A m)
    const int quad = lane >> 4;   // k-octet selector; token-row group in C

    // ---- one-time cooperative stage: 144 KB of B tiles + esq (single barrier) ----
    {
        const float4* gs = (const float4*)w;
        float4*       ls = (float4*)wlds;
        #pragma unroll 6
        for (int i = 0; i < NT_LDS * 4096 / 16 / 512; ++i)   // 18 rounds x 512 thr x 16 B
            ls[i * 512 + tid] = gs[i * 512 + tid];
        #pragma unroll
        for (int k = tid; k < K_CODES; k += 512) esq_s[k] = wesq[k];
    }
    __syncthreads();   // only barrier before the epilogue

    const int strip = blockIdx.x * 512 + wave * 64;   // 64 tokens per wave
    const int b  = strip >> 13;
    const int t0 = strip & 8191;

    // ---- A fragments: -2x -> ah (f16), ah_s = ah*2048 (exact), al = (x-ah)*2048 ----
    const float* xin = in + (size_t)b * DIM * T_LEN + t0;
    half8 a_h[4][2], a_hs[4][2], a_l[4][2];
    #pragma unroll
    for (int mt = 0; mt < 4; ++mt) {
        #pragma unroll
        for (int s = 0; s < 2; ++s) {
            half8 hh, hs, ll;
            #pragma unroll
            for (int j = 0; j < 8; ++j) {
                const int d = s * 32 + quad * 8 + j;
                float xv = -2.0f * xin[(size_t)d * T_LEN + mt * 16 + lo4];
                _Float16 h = (_Float16)xv;
                hh[j] = h;
                hs[j] = (_Float16)((float)h * LO_SCALE);            // exact exponent shift
                ll[j] = (_Float16)((xv - (float)h) * LO_SCALE);
            }
            a_h[mt][s] = hh;
            a_hs[mt][s] = hs;
            a_l[mt][s] = ll;
        }
    }

    float best[16];
    int   bidx[16];
    #pragma unroll
    for (int i = 0; i < 16; ++i) { best[i] = FLT_MAX; bidx[i] = 0; }

    // B frags (layout HW-verified r6): tile base + lane*8, frags at +0/+512/+1024/+1536
    const _Float16* wb_g = w    + (size_t)lane * 8;
    const _Float16* wb_l = wlds + (size_t)lane * 8;

    half8 Ah0, Ah1, Al0, Al1, Bh0, Bh1, Bl0, Bl1;
    float Ae, Be;
    auto loadB = [&](int ct, half8& h0, half8& h1, half8& l0, half8& l1, float& es) {
        if (ct < NT_LDS) {      // ds_read_b128 x4, conflict-free
            const _Float16* p = wb_l + (size_t)ct * 2048;
            h0 = *reinterpret_cast<const half8*>(p);          // hi, k 0..31
            h1 = *reinterpret_cast<const half8*>(p + 512);    // hi, k 32..63
            l0 = *reinterpret_cast<const half8*>(p + 1024);   // lo(x2048), k 0..31
            l1 = *reinterpret_cast<const half8*>(p + 1536);   // lo(x2048), k 32..63
        } else {                // global_load_dwordx4 x4 (L1/L2-hot)
            const _Float16* p = wb_g + (size_t)ct * 2048;
            h0 = *reinterpret_cast<const half8*>(p);
            h1 = *reinterpret_cast<const half8*>(p + 512);
            l0 = *reinterpret_cast<const half8*>(p + 1024);
            l1 = *reinterpret_cast<const half8*>(p + 1536);
        }
        es = esq_s[ct * 16 + lo4];
    };
    auto step = [&](const half8& h0, const half8& h1, const half8& l0,
                    const half8& l1, float es, int ct) {
        const int code = ct * 16 + lo4;
        #pragma unroll
        for (int mt = 0; mt < 4; ++mt) {
            f32x4 c = {es, es, es, es};        // 2048*||e||^2
            c = MFMA16(a_hs[mt][0], h0, c);    // 2048*ah*bh
            c = MFMA16(a_hs[mt][1], h1, c);
            c = MFMA16(a_h[mt][0], l0, c);     // ah*(2048*bl)
            c = MFMA16(a_h[mt][1], l1, c);
            c = MFMA16(a_l[mt][0], h0, c);     // (2048*al)*bh
            c = MFMA16(a_l[mt][1], h1, c);
            #pragma unroll
            for (int r = 0; r < 4; ++r) {
                float sc = c[r];                // scaled score, no fmaf needed
                const int i = mt * 4 + r;
                bool lt = sc < best[i];         // strict <: first occurrence wins
                best[i] = lt ? sc : best[i];
                bidx[i] = lt ? code : bidx[i];
            }
        }
    };

    // ping-pong: tile ct+1's 4 loads in flight during tile ct's 24 MFMAs
    loadB(0, Ah0, Ah1, Al0, Al1, Ae);
    loadB(1, Bh0, Bh1, Bl0, Bl1, Be);
    for (int p = 0; p < 31; ++p) {
        step(Ah0, Ah1, Al0, Al1, Ae, 2 * p);
        loadB(2 * p + 2, Ah0, Ah1, Al0, Al1, Ae);
        step(Bh0, Bh1, Bl0, Bl1, Be, 2 * p + 1);
        loadB(2 * p + 3, Bh0, Bh1, Bl0, Bl1, Be);
    }
    step(Ah0, Ah1, Al0, Al1, Ae, 62);
    step(Bh0, Bh1, Bl0, Bl1, Be, 63);

    // ---- cross-lane merge over the 16 code-residue lanes ----
    #pragma unroll
    for (int i = 0; i < 16; ++i) {
        float s = best[i];
        int  ix = bidx[i];
        #pragma unroll
        for (int off = 1; off < 16; off <<= 1) {
            float s2 = __shfl_xor(s, off, 64);
            int  ix2 = __shfl_xor(ix, off, 64);
            bool take = (s2 < s) || (s2 == s && ix2 < ix);  // tie -> lower index
            s  = take ? s2 : s;
            ix = take ? ix2 : ix;
        }
        if (lo4 == 0) {
            // token_local = mt*16 + quad*4 + r,  mt = i>>2, r = i&3
            idx_s[wave * 64 + (i >> 2) * 16 + quad * 4 + (i & 3)] = ix;
        }
    }
    __syncthreads();

    // ---- epilogue: 1 thread per token, gather exact fp32 row + coalesced stores ----
    const int token = blockIdx.x * 512 + tid;
    const int tb = token >> 13;
    const int tt = token & 8191;
    const int my_idx = idx_s[tid];

    out[(size_t)N_TOK * DIM + token] = (float)my_idx;   // index output

    const float* crow = cb + (size_t)my_idx * DIM;
    float* outv = out + (size_t)tb * DIM * T_LEN + tt;
    #pragma unroll
    for (int d0 = 0; d0 < DIM; d0 += 4) {
        float4 v = *reinterpret_cast<const float4*>(crow + d0);  // L2-hot gather
        outv[(size_t)(d0 + 0) * T_LEN] = v.x;
        outv[(size_t)(d0 + 1) * T_LEN] = v.y;
        outv[(size_t)(d0 + 2) * T_LEN] = v.z;
        outv[(size_t)(d0 + 3) * T_LEN] = v.w;
    }
}

extern "C" void kernel_launch(void* const* d_in, const int* in_sizes, int n_in,
                              void* d_out, int out_size, void* d_ws, size_t ws_size,
                              hipStream_t stream) {
    const float* in = (const float*)d_in[0];   // (16, 64, 8192) fp32
    const float* cb = (const float*)d_in[1];   // (1024, 64) fp32
    float* out = (float*)d_out;

    _Float16* w   = (_Float16*)d_ws;                       // 64 tiles * 4 KB = 256 KB
    float*   wesq = (float*)((char*)d_ws + 64 * 4096);     // 4 KB

    static bool attr_done = false;
    if (!attr_done) {
        hipFuncSetAttribute(reinterpret_cast<const void*>(vq_main),
                            hipFuncAttributeMaxDynamicSharedMemorySize, LDS_BYTES);
        attr_done = true;
    }

    vq_prep<<<dim3(64), dim3(256), 0, stream>>>(cb, w, wesq);
    vq_main<<<dim3(N_TOK / 512), dim3(512), LDS_BYTES, stream>>>(in, cb, w, wesq, out);
}

// Round 2
// 128.738 us; speedup vs baseline: 1.0321x; 1.0321x over previous
//
#include <hip/hip_runtime.h>
#include <float.h>

#define K_CODES 1024
#define DIM 64
#define T_LEN 8192
#define N_TOK 131072          // 16 * 8192 tokens
#define LO_SCALE 2048.0f

typedef _Float16 half8 __attribute__((ext_vector_type(8)));  // 4 VGPRs: MFMA A/B frag
typedef float    f32x4 __attribute__((ext_vector_type(4)));  // MFMA C/D frag

#define MFMA16(a, b, c) __builtin_amdgcn_mfma_f32_16x16x32_f16((a), (b), (c), 0, 0, 0)

// ---------------- prep: codebook -> tiled f16 hi/lo + 2048*e_sq ----------------
// Tile ct (16 codes) = 4 KB contiguous: hi[q=0..7][code=0..15][j=0..7], lo(x2048) at +1024.
// wesq stores 2048*||e||^2 (exact power-of-2 scale) for the scaled-score argmin.
__global__ void vq_prep(const float* __restrict__ cb,
                        _Float16* __restrict__ w,
                        float* __restrict__ wesq) {
    __shared__ float part[128];
    const int ct   = blockIdx.x;
    const int r    = threadIdx.x;
    const int halF = r >> 7;
    const int rr   = r & 127;
    const int q    = rr >> 4;
    const int code = rr & 15;

    const float* src = cb + (size_t)(ct * 16 + code) * DIM + q * 8;
    float4 v0 = *reinterpret_cast<const float4*>(src);
    float4 v1 = *reinterpret_cast<const float4*>(src + 4);
    float x[8] = {v0.x, v0.y, v0.z, v0.w, v1.x, v1.y, v1.z, v1.w};

    half8 o;
    float psum = 0.0f;
    #pragma unroll
    for (int j = 0; j < 8; ++j) {
        _Float16 h = (_Float16)x[j];
        o[j] = halF ? (_Float16)((x[j] - (float)h) * LO_SCALE) : h;  // (x-h) exact in fp32
        psum = fmaf(x[j], x[j], psum);
    }
    *reinterpret_cast<half8*>(w + (size_t)ct * 2048 + halF * 1024 + q * 128 + code * 8) = o;

    if (halF == 0) part[rr] = psum;
    __syncthreads();
    if (r < 16) {
        float s = 0.0f;
        #pragma unroll
        for (int q2 = 0; q2 < 8; ++q2) s += part[q2 * 16 + r];
        wesq[ct * 16 + r] = s * LO_SCALE;   // pre-scaled: score' = 2048 * score
    }
}

// ---------------- main: global-direct B + INTERLEAVED mt chains + 3-op argmin ----------------
// r1 lesson: B-load latency is NOT the stall (LDS-staging 36 tiles was neutral). New theory:
// the 6-deep serial MFMA chain per mt, with mt chains executed sequentially, leaves the matrix
// pipe latency-bound at 2 waves/SIMD (MfmaUtil 33%). Fix: pass-outer / mt-inner issue order --
// 4 independent accumulator chains interleaved, so each chain's next link has ~4 issue slots of
// slack >> MFMA latency. Numerics bit-identical: same MFMA set, same order within each chain.
__global__ __launch_bounds__(256, 2)
void vq_main(const float* __restrict__ in,
             const float* __restrict__ cb,
             const _Float16* __restrict__ w,
             const float* __restrict__ wesq,
             float* __restrict__ out) {
    __shared__ float esq_s[K_CODES];   // 4 KB (scaled x2048)
    __shared__ int   idx_s[256];

    const int tid  = threadIdx.x;
    const int wave = tid >> 6;
    const int lane = tid & 63;
    const int lo4  = lane & 15;   // code residue (C col) / token residue (A m)
    const int quad = lane >> 4;   // k-octet selector; token-row group in C

    for (int k = tid; k < K_CODES; k += 256) esq_s[k] = wesq[k];
    __syncthreads();   // only barrier before the epilogue

    const int strip = blockIdx.x * 256 + wave * 64;   // 64 tokens per wave
    const int b  = strip >> 13;
    const int t0 = strip & 8191;

    // ---- A fragments: -2x -> ah (f16), ah_s = ah*2048 (exact), al = (x-ah)*2048 ----
    const float* xin = in + (size_t)b * DIM * T_LEN + t0;
    half8 a_h[4][2], a_hs[4][2], a_l[4][2];
    #pragma unroll
    for (int mt = 0; mt < 4; ++mt) {
        #pragma unroll
        for (int s = 0; s < 2; ++s) {
            half8 hh, hs, ll;
            #pragma unroll
            for (int j = 0; j < 8; ++j) {
                const int d = s * 32 + quad * 8 + j;
                float xv = -2.0f * xin[(size_t)d * T_LEN + mt * 16 + lo4];
                _Float16 h = (_Float16)xv;
                hh[j] = h;
                hs[j] = (_Float16)((float)h * LO_SCALE);            // exact exponent shift
                ll[j] = (_Float16)((xv - (float)h) * LO_SCALE);
            }
            a_h[mt][s] = hh;
            a_hs[mt][s] = hs;
            a_l[mt][s] = ll;
        }
    }

    float best[16];
    int   bidx[16];
    #pragma unroll
    for (int i = 0; i < 16; ++i) { best[i] = FLT_MAX; bidx[i] = 0; }

    // B frags (layout HW-verified r6): tile base + lane*8, frags at +0/+512/+1024/+1536
    const _Float16* wb = w + (size_t)lane * 8;

    half8 Ah0, Ah1, Al0, Al1, Bh0, Bh1, Bl0, Bl1;
    float Ae, Be;
    auto loadB = [&](int ct, half8& h0, half8& h1, half8& l0, half8& l1, float& es) {
        const _Float16* p = wb + (size_t)ct * 2048;
        h0 = *reinterpret_cast<const half8*>(p);          // hi, k 0..31
        h1 = *reinterpret_cast<const half8*>(p + 512);    // hi, k 32..63
        l0 = *reinterpret_cast<const half8*>(p + 1024);   // lo(x2048), k 0..31
        l1 = *reinterpret_cast<const half8*>(p + 1536);   // lo(x2048), k 32..63
        es = esq_s[ct * 16 + lo4];
    };
    // Interleaved issue: 4 independent accumulator chains, pass-outer / mt-inner.
    // Same per-chain MFMA order as before -> bit-identical scores.
    auto step = [&](const half8& h0, const half8& h1, const half8& l0,
                    const half8& l1, float es, int ct) {
        const int code = ct * 16 + lo4;
        f32x4 c0 = {es, es, es, es}, c1 = {es, es, es, es};
        f32x4 c2 = {es, es, es, es}, c3 = {es, es, es, es};
        c0 = MFMA16(a_hs[0][0], h0, c0);   // pass 1: 2048*ah*bh (k 0..31)
        c1 = MFMA16(a_hs[1][0], h0, c1);
        c2 = MFMA16(a_hs[2][0], h0, c2);
        c3 = MFMA16(a_hs[3][0], h0, c3);
        c0 = MFMA16(a_hs[0][1], h1, c0);   // pass 2: 2048*ah*bh (k 32..63)
        c1 = MFMA16(a_hs[1][1], h1, c1);
        c2 = MFMA16(a_hs[2][1], h1, c2);
        c3 = MFMA16(a_hs[3][1], h1, c3);
        c0 = MFMA16(a_h[0][0], l0, c0);    // pass 3: ah*(2048*bl)
        c1 = MFMA16(a_h[1][0], l0, c1);
        c2 = MFMA16(a_h[2][0], l0, c2);
        c3 = MFMA16(a_h[3][0], l0, c3);
        c0 = MFMA16(a_h[0][1], l1, c0);    // pass 4
        c1 = MFMA16(a_h[1][1], l1, c1);
        c2 = MFMA16(a_h[2][1], l1, c2);
        c3 = MFMA16(a_h[3][1], l1, c3);
        c0 = MFMA16(a_l[0][0], h0, c0);    // pass 5: (2048*al)*bh
        c1 = MFMA16(a_l[1][0], h0, c1);
        c2 = MFMA16(a_l[2][0], h0, c2);
        c3 = MFMA16(a_l[3][0], h0, c3);
        c0 = MFMA16(a_l[0][1], h1, c0);    // pass 6
        c1 = MFMA16(a_l[1][1], h1, c1);
        c2 = MFMA16(a_l[2][1], h1, c2);
        c3 = MFMA16(a_l[3][1], h1, c3);
        f32x4 cc[4] = {c0, c1, c2, c3};
        #pragma unroll
        for (int mt = 0; mt < 4; ++mt) {
            #pragma unroll
            for (int r = 0; r < 4; ++r) {
                float sc = cc[mt][r];           // scaled score, no fmaf needed
                const int i = mt * 4 + r;
                bool lt = sc < best[i];         // strict <: first occurrence wins
                best[i] = lt ? sc : best[i];
                bidx[i] = lt ? code : bidx[i];
            }
        }
    };

    // ping-pong: tile ct+1's 4 global loads in flight during tile ct's 24 MFMAs
    loadB(0, Ah0, Ah1, Al0, Al1, Ae);
    loadB(1, Bh0, Bh1, Bl0, Bl1, Be);
    for (int p = 0; p < 31; ++p) {
        step(Ah0, Ah1, Al0, Al1, Ae, 2 * p);
        loadB(2 * p + 2, Ah0, Ah1, Al0, Al1, Ae);
        step(Bh0, Bh1, Bl0, Bl1, Be, 2 * p + 1);
        loadB(2 * p + 3, Bh0, Bh1, Bl0, Bl1, Be);
    }
    step(Ah0, Ah1, Al0, Al1, Ae, 62);
    step(Bh0, Bh1, Bl0, Bl1, Be, 63);

    // ---- cross-lane merge over the 16 code-residue lanes ----
    #pragma unroll
    for (int i = 0; i < 16; ++i) {
        float s = best[i];
        int  ix = bidx[i];
        #pragma unroll
        for (int off = 1; off < 16; off <<= 1) {
            float s2 = __shfl_xor(s, off, 64);
            int  ix2 = __shfl_xor(ix, off, 64);
            bool take = (s2 < s) || (s2 == s && ix2 < ix);  // tie -> lower index
            s  = take ? s2 : s;
            ix = take ? ix2 : ix;
        }
        if (lo4 == 0) {
            // token_local = mt*16 + quad*4 + r,  mt = i>>2, r = i&3
            idx_s[wave * 64 + (i >> 2) * 16 + quad * 4 + (i & 3)] = ix;
        }
    }
    __syncthreads();

    // ---- epilogue: 1 thread per token, gather exact fp32 row + coalesced stores ----
    const int token = blockIdx.x * 256 + tid;
    const int tb = token >> 13;
    const int tt = token & 8191;
    const int my_idx = idx_s[tid];

    out[(size_t)N_TOK * DIM + token] = (float)my_idx;   // index output

    const float* crow = cb + (size_t)my_idx * DIM;
    float* outv = out + (size_t)tb * DIM * T_LEN + tt;
    #pragma unroll
    for (int d0 = 0; d0 < DIM; d0 += 4) {
        float4 v = *reinterpret_cast<const float4*>(crow + d0);  // L2-hot gather
        outv[(size_t)(d0 + 0) * T_LEN] = v.x;
        outv[(size_t)(d0 + 1) * T_LEN] = v.y;
        outv[(size_t)(d0 + 2) * T_LEN] = v.z;
        outv[(size_t)(d0 + 3) * T_LEN] = v.w;
    }
}

extern "C" void kernel_launch(void* const* d_in, const int* in_sizes, int n_in,
                              void* d_out, int out_size, void* d_ws, size_t ws_size,
                              hipStream_t stream) {
    const float* in = (const float*)d_in[0];   // (16, 64, 8192) fp32
    const float* cb = (const float*)d_in[1];   // (1024, 64) fp32
    float* out = (float*)d_out;

    _Float16* w   = (_Float16*)d_ws;                       // 64 tiles * 4 KB = 256 KB
    float*   wesq = (float*)((char*)d_ws + 64 * 4096);     // 4 KB

    vq_prep<<<dim3(64), dim3(256), 0, stream>>>(cb, w, wesq);
    vq_main<<<dim3(N_TOK / 256), dim3(256), 0, stream>>>(in, cb, w, wesq, out);
}